// Round 1
// baseline (312.960 us; speedup 1.0000x reference)
//
#include <hip/hip_runtime.h>

#define HH 128
#define WW 128
#define CIN 256
#define COUT 256
#define KTOT 2304   // 9 * 256, k = kk*256 + ci
#define HW (HH * WW)
#define NIT 36      // 9 taps * 4 channel-chunks of 64

typedef __attribute__((ext_vector_type(8))) short short8;
typedef __attribute__((ext_vector_type(4))) float f32x4;

__device__ __forceinline__ unsigned rne_bf16(float f) {
  unsigned u = __float_as_uint(f);
  return (u + 0x7FFFu + ((u >> 16) & 1u)) >> 16;
}
__device__ __forceinline__ unsigned pack_bf16x2(float lo, float hi) {
  return rne_bf16(lo) | (rne_bf16(hi) << 16);
}
// single-instruction RNE pack (bitwise identical to rne_bf16 pair)
__device__ __forceinline__ unsigned cvt_pk_bf16(float lo, float hi) {
  unsigned r;
  asm("v_cvt_pk_bf16_f32 %0, %1, %2" : "=v"(r) : "v"(lo), "v"(hi));
  return r;
}
__device__ __forceinline__ float bflo(unsigned u) { return __uint_as_float(u << 16); }
__device__ __forceinline__ float bfhi(unsigned u) { return __uint_as_float(u & 0xFFFF0000u); }

__device__ __forceinline__ unsigned blend2(unsigned a, unsigned b, unsigned c, unsigned d,
                                           float w00, float w01, float w10, float w11) {
  float lo = w00 * bflo(a) + w01 * bflo(b) + w10 * bflo(c) + w11 * bflo(d);
  float hi = w00 * bfhi(a) + w01 * bfhi(b) + w10 * bfhi(c) + w11 * bfhi(d);
  return cvt_pk_bf16(lo, hi);
}

// x [N][CIN][H][W] fp32 -> xt [N][H][W][CIN] bf16.
__global__ void transpose_x(const float* __restrict__ x, unsigned short* __restrict__ xt) {
  int b = blockIdx.x;
  int cg = b & 3;
  int nh = b >> 2;
  int n = nh >> 7, h = nh & 127;
  int c0 = cg << 6;
  __shared__ float tile[64][129];
  const float* xp = x + ((size_t)n * CIN * HH + h) * WW;
  for (int e = threadIdx.x; e < 64 * 128; e += 256) {
    int w = e & 127, ci = e >> 7;
    tile[ci][w] = xp[(size_t)(c0 + ci) * HW + w];
  }
  __syncthreads();
  unsigned* dst = (unsigned*)(xt + ((size_t)(n * HH + h) * WW) * CIN + c0);
  for (int e = threadIdx.x; e < 128 * 32; e += 256) {
    int w = e >> 5, cp = e & 31;
    dst[w * (CIN / 2) + cp] = pack_bf16x2(tile[2 * cp][w], tile[2 * cp + 1][w]);
  }
}

// weight [COUT][CIN][3][3] fp32 -> wT [COUT][kk*256+ci] bf16
__global__ void transform_w(const float* __restrict__ wsrc, unsigned short* __restrict__ wT) {
  int o = blockIdx.x * 256 + threadIdx.x;
  if (o >= COUT * KTOT) return;
  int co = o / KTOT;
  int r = o - co * KTOT;
  int kk = r >> 8, ci = r & 255;
  wT[o] = rne_bf16(wsrc[(size_t)(co * CIN + ci) * 9 + kk]);
}

// R5: BN=256 (bn split removed -> blend + gather dedup 2x), 64x64 wave tiles
// (halves LDS frag-reads per MFMA), XOR-swizzled 128B LDS rows (b128 bank
// floor), wT register-prefetch, lgkmcnt-only barriers so global prefetch
// stays in flight across barriers (no vmcnt(0) drain).
// Grid 512 = 2 blocks/CU; each XCD gets a contiguous 32-row band of xt.
__global__ __launch_bounds__(256, 2) void fused_deform_gemm(
    const float* __restrict__ obb, const unsigned short* __restrict__ xt,
    const unsigned short* __restrict__ wT, float* __restrict__ out,
    const int* __restrict__ stride_p) {
  int g = blockIdx.x;
  int xcd = g & 7, li = g >> 3;
  int u = xcd * 64 + li;   // 0..511
  int mh = u & 1;          // which half of the image row
  int bm = u >> 1;         // row id 0..255
  int n = bm >> 7, h = bm & 127;
  int tid = threadIdx.x;

  // 128B rows, physical byte = row*128 + (colbyte ^ ((row&7)<<4))
  __shared__ __align__(16) unsigned short Alds[64 * 64];    // 8 KB
  __shared__ __align__(16) unsigned short Blds[256 * 64];   // 32 KB
  __shared__ float pcx[64], pcy[64], pA[64], pB[64], pC[64], pD[64];

  float inv_s = 1.0f / (float)stride_p[0];

  if (tid < 64) {
    int w = mh * 64 + tid;
    const float* op = obb + ((size_t)n * 5 * HH + h) * WW + w;
    float xc = op[0] * inv_s;
    float yc = op[(size_t)1 * HW] * inv_s;
    float bw = op[(size_t)2 * HW] * inv_s;
    float bh = op[(size_t)3 * HW] * inv_s;
    float th = op[(size_t)4 * HW];
    float sn, cs;
    sincosf(th, &sn, &cs);
    float dw = bw * (1.0f / 3.0f), dh = bh * (1.0f / 3.0f);
    pcx[tid] = xc; pcy[tid] = yc;
    pA[tid] = dw * cs; pB[tid] = dh * sn;
    pC[tid] = dw * sn; pD[tid] = dh * cs;
  }

  f32x4 acc[4][4] = {};

  int lane = tid & 63;
  int wv = tid >> 6;        // 0..3
  int wn = wv * 64;         // wave's cout base (wave tile 64px x 64co)
  int l15 = lane & 15, l4 = lane >> 4;

  // A-build lane map: 8 lanes per pixel, each lane owns one 16B (8-ch) chunk.
  int chunk8 = (lane & 7) * 8;
  int prow = wv * 8 + (lane >> 3); // 0..31; pixel p = j*32 + prow

  // B staging: 8 x 16B per thread (256 rows x 64 k-elems)
  int wToff[8];
  int BldsOff[8];
#pragma unroll
  for (int r2 = 0; r2 < 8; ++r2) {
    int idx = r2 * 256 + tid;
    int row = idx >> 3, kc8 = idx & 7;
    wToff[r2] = row * KTOT + kc8 * 8;
    BldsOff[r2] = row * 128 + ((kc8 * 16) ^ ((row & 7) << 4));
  }
  // A write offsets (2 pixel-jobs)
  int AldsOff[2];
#pragma unroll
  for (int j = 0; j < 2; ++j) {
    int row = j * 32 + prow;
    AldsOff[j] = row * 128 + ((chunk8 * 2) ^ ((row & 7) << 4));
  }
  // fragment-read column byte offsets (same XOR class for A and B: row&7 == l15&7)
  int rdXor = (l15 & 7) << 4;
  int rc0 = (l4 * 16) ^ rdXor;        // ks = 0
  int rc1 = (64 + l4 * 16) ^ rdXor;   // ks = 32

  float wgt_[2][4]; // bilinear weights per job
  int boff[2][4];   // corner base element offsets per job
  uint4 pf[2][4];   // prefetched corner data (job, corner)
  uint4 aw[2];      // blended A chunks awaiting staging
  uint4 Bw[8];      // prefetched wT data awaiting staging

  __syncthreads(); // params ready

  auto prep = [&](int kk) {
    float fky = (float)(kk / 3 - 1);
    float fkx = (float)(kk % 3 - 1);
#pragma unroll
    for (int j = 0; j < 2; ++j) {
      int p = j * 32 + prow;
      float sx = pcx[p] + fkx * pA[p] - fky * pB[p];
      float sy = pcy[p] + fkx * pC[p] + fky * pD[p];
      float fx = floorf(sx), fy = floorf(sy);
      float lx = sx - fx, ly = sy - fy;
      int x0 = (int)fx, y0 = (int)fy;
      float vy0 = (y0 >= 0 && y0 < HH) ? 1.0f : 0.0f;
      float vy1 = (y0 >= -1 && y0 < HH - 1) ? 1.0f : 0.0f;
      float vx0 = (x0 >= 0 && x0 < WW) ? 1.0f : 0.0f;
      float vx1 = (x0 >= -1 && x0 < WW - 1) ? 1.0f : 0.0f;
      wgt_[j][0] = (1.0f - ly) * (1.0f - lx) * vy0 * vx0;
      wgt_[j][1] = (1.0f - ly) * lx * vy0 * vx1;
      wgt_[j][2] = ly * (1.0f - lx) * vy1 * vx0;
      wgt_[j][3] = ly * lx * vy1 * vx1;
      int xc0 = min(max(x0, 0), WW - 1), xc1 = min(max(x0 + 1, 0), WW - 1);
      int yc0 = min(max(y0, 0), HH - 1), yc1 = min(max(y0 + 1, 0), HH - 1);
      int rb0 = (n * HH + yc0) * WW, rb1 = (n * HH + yc1) * WW;
      boff[j][0] = (rb0 + xc0) * CIN;
      boff[j][1] = (rb0 + xc1) * CIN;
      boff[j][2] = (rb1 + xc0) * CIN;
      boff[j][3] = (rb1 + xc1) * CIN;
    }
  };

  auto issueA = [&](int cc) {
    int co = cc * 64 + chunk8;
#pragma unroll
    for (int j = 0; j < 2; ++j)
#pragma unroll
      for (int c = 0; c < 4; ++c)
        pf[j][c] = *(const uint4*)(xt + boff[j][c] + co);
  };

  auto loadB = [&](int itn) {
    const unsigned short* p = wT + itn * 64;
#pragma unroll
    for (int r2 = 0; r2 < 8; ++r2)
      Bw[r2] = *(const uint4*)(p + wToff[r2]);
  };

  auto blendA = [&]() {
#pragma unroll
    for (int j = 0; j < 2; ++j) {
      uint4 r;
      r.x = blend2(pf[j][0].x, pf[j][1].x, pf[j][2].x, pf[j][3].x,
                   wgt_[j][0], wgt_[j][1], wgt_[j][2], wgt_[j][3]);
      r.y = blend2(pf[j][0].y, pf[j][1].y, pf[j][2].y, pf[j][3].y,
                   wgt_[j][0], wgt_[j][1], wgt_[j][2], wgt_[j][3]);
      r.z = blend2(pf[j][0].z, pf[j][1].z, pf[j][2].z, pf[j][3].z,
                   wgt_[j][0], wgt_[j][1], wgt_[j][2], wgt_[j][3]);
      r.w = blend2(pf[j][0].w, pf[j][1].w, pf[j][2].w, pf[j][3].w,
                   wgt_[j][0], wgt_[j][1], wgt_[j][2], wgt_[j][3]);
      aw[j] = r;
    }
  };

  // prologue: A(0) blended into aw, B(0) in Bw, gather(1) in flight
  prep(0);
  issueA(0);
  loadB(0);
  blendA();
  issueA(1);

  char* AB = (char*)Alds;
  char* BB = (char*)Blds;

  for (int it = 0; it < NIT; ++it) {
    // ---- phase A: stage (pure ds_writes; wT(it+1) issued for next iter) ----
#pragma unroll
    for (int j = 0; j < 2; ++j) *(uint4*)(AB + AldsOff[j]) = aw[j];
#pragma unroll
    for (int r2 = 0; r2 < 8; ++r2) *(uint4*)(BB + BldsOff[r2]) = Bw[r2];
    if (it + 1 < NIT) loadB(it + 1);
    asm volatile("s_waitcnt lgkmcnt(0)" ::: "memory");
    __builtin_amdgcn_s_barrier();

    // ---- phase B: blend next A tile, issue gather(it+2), MFMA current ----
    int nx = it + 1;
    if (nx < NIT) {
      blendA();                        // consumes pf (data for nx)
      int nn = it + 2;
      if (nn < NIT) {
        if ((nn & 3) == 0) prep(nn >> 2);
        issueA(nn & 3);                // lands during next phase A/B
      }
    }

#pragma unroll
    for (int ksi = 0; ksi < 2; ++ksi) {
      int rc = ksi ? rc1 : rc0;
      short8 af[4];
#pragma unroll
      for (int i = 0; i < 4; ++i)
        af[i] = *(const short8*)(AB + (i * 16 + l15) * 128 + rc);
#pragma unroll
      for (int j = 0; j < 4; ++j) {
        short8 bf = *(const short8*)(BB + (wn + j * 16 + l15) * 128 + rc);
#pragma unroll
        for (int i = 0; i < 4; ++i)
          acc[i][j] = __builtin_amdgcn_mfma_f32_16x16x32_bf16(af[i], bf, acc[i][j], 0, 0, 0);
      }
    }
    asm volatile("s_waitcnt lgkmcnt(0)" ::: "memory");
    __builtin_amdgcn_s_barrier();
  }

  // ---- epilogue: out[n][co][h][w], float4 along w ----
  float* outp = out + (size_t)n * COUT * HW + (size_t)h * WW + mh * 64;
#pragma unroll
  for (int i = 0; i < 4; ++i) {
    int w0 = i * 16 + l4 * 4;
#pragma unroll
    for (int j = 0; j < 4; ++j) {
      int co = wn + j * 16 + l15;
      *(f32x4*)(outp + co * HW + w0) = acc[i][j];
    }
  }
}

extern "C" void kernel_launch(void* const* d_in, const int* in_sizes, int n_in,
                              void* d_out, int out_size, void* d_ws, size_t ws_size,
                              hipStream_t stream) {
  const float* x = (const float*)d_in[0];
  const float* obb = (const float*)d_in[1];
  const float* wgt = (const float*)d_in[2];
  const int* stridep = (const int*)d_in[3];
  float* out = (float*)d_out;

  unsigned short* xt = (unsigned short*)d_ws;          // 2*128*128*256 bf16 = 16.8 MB
  unsigned short* wT = xt + (size_t)2 * HH * WW * CIN; // 256*2304 bf16 = 1.2 MB

  transpose_x<<<dim3(2 * HH * 4), 256, 0, stream>>>(x, xt);
  transform_w<<<dim3((COUT * KTOT + 255) / 256), 256, 0, stream>>>(wgt, wT);
  fused_deform_gemm<<<dim3(2 * HH * 2), 256, 0, stream>>>(obb, xt, wT, out, stridep);
}

// Round 2
// 153.152 us; speedup vs baseline: 2.0435x; 2.0435x over previous
//
#include <hip/hip_runtime.h>

#define HH 128
#define WW 128
#define CIN 256
#define COUT 256
#define KTOT 2304   // 9 * 256, k = kk*256 + ci
#define HW (HH * WW)
#define NIT 36      // 9 taps * 4 channel-chunks of 64

typedef __attribute__((ext_vector_type(8))) short short8;
typedef __attribute__((ext_vector_type(4))) float f32x4;

__device__ __forceinline__ unsigned rne_bf16(float f) {
  unsigned u = __float_as_uint(f);
  return (u + 0x7FFFu + ((u >> 16) & 1u)) >> 16;
}
__device__ __forceinline__ unsigned pack_bf16x2(float lo, float hi) {
  return rne_bf16(lo) | (rne_bf16(hi) << 16);
}
// single-instruction RNE pack (bitwise identical to rne_bf16 pair)
__device__ __forceinline__ unsigned cvt_pk_bf16(float lo, float hi) {
  unsigned r;
  asm("v_cvt_pk_bf16_f32 %0, %1, %2" : "=v"(r) : "v"(lo), "v"(hi));
  return r;
}
__device__ __forceinline__ float bflo(unsigned u) { return __uint_as_float(u << 16); }
__device__ __forceinline__ float bfhi(unsigned u) { return __uint_as_float(u & 0xFFFF0000u); }

__device__ __forceinline__ unsigned blend2(unsigned a, unsigned b, unsigned c, unsigned d,
                                           float w00, float w01, float w10, float w11) {
  float lo = w00 * bflo(a) + w01 * bflo(b) + w10 * bflo(c) + w11 * bflo(d);
  float hi = w00 * bfhi(a) + w01 * bfhi(b) + w10 * bfhi(c) + w11 * bfhi(d);
  return cvt_pk_bf16(lo, hi);
}

__device__ __forceinline__ void glds16(const unsigned short* g, unsigned short* l) {
  __builtin_amdgcn_global_load_lds(
      (const __attribute__((address_space(1))) void*)g,
      (__attribute__((address_space(3))) void*)l, 16, 0, 0);
}

// Merged prep: blocks [0,1024): x [N][CIN][H][W] fp32 -> xt [N][H][W][CIN] bf16
//              blocks [1024,3328): weight [COUT][CIN][3][3] -> wT [COUT][kk*256+ci]
__global__ void prep_inputs(const float* __restrict__ x, const float* __restrict__ wsrc,
                            unsigned short* __restrict__ xt, unsigned short* __restrict__ wT) {
  int b = blockIdx.x;
  __shared__ float tile[64][129];
  if (b < 1024) {
    int cg = b & 3;
    int nh = b >> 2;
    int n = nh >> 7, h = nh & 127;
    int c0 = cg << 6;
    const float* xp = x + ((size_t)n * CIN * HH + h) * WW;
    for (int e = threadIdx.x; e < 64 * 128; e += 256) {
      int w = e & 127, ci = e >> 7;
      tile[ci][w] = xp[(size_t)(c0 + ci) * HW + w];
    }
    __syncthreads();
    unsigned* dst = (unsigned*)(xt + ((size_t)(n * HH + h) * WW) * CIN + c0);
    for (int e = threadIdx.x; e < 128 * 32; e += 256) {
      int w = e >> 5, cp = e & 31;
      dst[w * (CIN / 2) + cp] = pack_bf16x2(tile[2 * cp][w], tile[2 * cp + 1][w]);
    }
  } else {
    int o = (b - 1024) * 256 + threadIdx.x;
    if (o >= COUT * KTOT) return;
    int co = o / KTOT;
    int r = o - co * KTOT;
    int kk = r >> 8, ci = r & 255;
    wT[o] = rne_bf16(wsrc[(size_t)(co * CIN + ci) * 9 + kk]);
  }
}

// R6: 512 threads (8 waves), wave tile 32px x 64co -> acc[2][4]=32 VGPR.
// One pixel-job per thread -> pf[4]=16 VGPR. B staged via global_load_lds
// with pre-swizzled per-lane SOURCE (linear LDS dest, XOR involution on
// source == XOR on read). Goal: kill the R5 scratch spills (507MB writes).
// LDS 41.5KB, target <=128 VGPR -> 2 blocks/CU (16 waves/CU).
__global__ __launch_bounds__(512, 2) void fused_deform_gemm(
    const float* __restrict__ obb, const unsigned short* __restrict__ xt,
    const unsigned short* __restrict__ wT, float* __restrict__ out,
    const int* __restrict__ stride_p) {
  int g = blockIdx.x;
  int xcd = g & 7, li = g >> 3;
  int u = xcd * 64 + li;   // 0..511; each XCD gets a contiguous 32-row band
  int mh = u & 1;          // which half of the image row
  int bm = u >> 1;         // row id 0..255
  int n = bm >> 7, h = bm & 127;
  int tid = threadIdx.x;

  // 128B rows, physical byte = row*128 + (colbyte ^ ((row&7)<<4))
  __shared__ __align__(16) unsigned short Alds[64 * 64];    // 8 KB
  __shared__ __align__(16) unsigned short Blds[256 * 64];   // 32 KB
  __shared__ float pcx[64], pcy[64], pA[64], pB[64], pC[64], pD[64];

  float inv_s = 1.0f / (float)stride_p[0];

  if (tid < 64) {
    int w = mh * 64 + tid;
    const float* op = obb + ((size_t)n * 5 * HH + h) * WW + w;
    float xc = op[0] * inv_s;
    float yc = op[(size_t)1 * HW] * inv_s;
    float bw = op[(size_t)2 * HW] * inv_s;
    float bh = op[(size_t)3 * HW] * inv_s;
    float th = op[(size_t)4 * HW];
    float sn, cs;
    sincosf(th, &sn, &cs);
    float dw = bw * (1.0f / 3.0f), dh = bh * (1.0f / 3.0f);
    pcx[tid] = xc; pcy[tid] = yc;
    pA[tid] = dw * cs; pB[tid] = dh * sn;
    pC[tid] = dw * sn; pD[tid] = dh * cs;
  }

  f32x4 acc[2][4] = {};

  int lane = tid & 63;
  int wv = tid >> 6;          // 0..7
  int wm = (wv & 1) * 32;     // wave pixel base
  int wn = (wv >> 1) * 64;    // wave cout base
  int l15 = lane & 15, l4 = lane >> 4;

  // A-build: 8 lanes per pixel, one 16B (8-channel) chunk per thread.
  int chunk8 = (lane & 7) * 8;
  int p = wv * 8 + (lane >> 3);            // this thread's pixel, 0..63
  int AldsOff = p * 128 + (((lane & 7) * 16) ^ ((p & 7) << 4));

  // B staging via global_load_lds: 4 rounds, each wave writes 8 rows (1KB).
  // lane -> row t*64 + wv*8 + (lane>>3), phys col (lane&7)*16; source holds
  // logical col = phys ^ ((row&7)<<4).
  int cbl = ((lane & 7) * 16) ^ ((lane >> 3) << 4);
  int BsrcC[4];   // per-thread constant byte offset into wT (+ it*128 at runtime)
  int BldsC[4];   // wave-uniform LDS byte offset
#pragma unroll
  for (int t = 0; t < 4; ++t) {
    int row = t * 64 + wv * 8 + (lane >> 3);
    BsrcC[t] = row * (KTOT * 2) + cbl;
    BldsC[t] = (t * 64 + wv * 8) * 128;
  }

  // fragment-read column byte offsets (row&7 == l15&7 for all frag rows)
  int rdXor = (l15 & 7) << 4;
  int rc0 = (l4 * 16) ^ rdXor;        // ks = 0
  int rc1 = (64 + l4 * 16) ^ rdXor;   // ks = 32

  float wgt_[4];  // bilinear weights for this thread's pixel, current tap
  int boff[4];    // corner base element offsets
  uint4 pf[4];    // prefetched corner data
  uint4 aw;       // blended A chunk awaiting staging

  __syncthreads(); // params ready

  auto prep = [&](int kk) {
    float fky = (float)(kk / 3 - 1);
    float fkx = (float)(kk % 3 - 1);
    float sx = pcx[p] + fkx * pA[p] - fky * pB[p];
    float sy = pcy[p] + fkx * pC[p] + fky * pD[p];
    float fx = floorf(sx), fy = floorf(sy);
    float lx = sx - fx, ly = sy - fy;
    int x0 = (int)fx, y0 = (int)fy;
    float vy0 = (y0 >= 0 && y0 < HH) ? 1.0f : 0.0f;
    float vy1 = (y0 >= -1 && y0 < HH - 1) ? 1.0f : 0.0f;
    float vx0 = (x0 >= 0 && x0 < WW) ? 1.0f : 0.0f;
    float vx1 = (x0 >= -1 && x0 < WW - 1) ? 1.0f : 0.0f;
    wgt_[0] = (1.0f - ly) * (1.0f - lx) * vy0 * vx0;
    wgt_[1] = (1.0f - ly) * lx * vy0 * vx1;
    wgt_[2] = ly * (1.0f - lx) * vy1 * vx0;
    wgt_[3] = ly * lx * vy1 * vx1;
    int xc0 = min(max(x0, 0), WW - 1), xc1 = min(max(x0 + 1, 0), WW - 1);
    int yc0 = min(max(y0, 0), HH - 1), yc1 = min(max(y0 + 1, 0), HH - 1);
    int rb0 = (n * HH + yc0) * WW, rb1 = (n * HH + yc1) * WW;
    boff[0] = (rb0 + xc0) * CIN;
    boff[1] = (rb0 + xc1) * CIN;
    boff[2] = (rb1 + xc0) * CIN;
    boff[3] = (rb1 + xc1) * CIN;
  };

  auto issueA = [&](int cc) {
    int co = cc * 64 + chunk8;
#pragma unroll
    for (int c = 0; c < 4; ++c)
      pf[c] = *(const uint4*)(xt + boff[c] + co);
  };

  auto blendA = [&]() {
    uint4 r;
    r.x = blend2(pf[0].x, pf[1].x, pf[2].x, pf[3].x, wgt_[0], wgt_[1], wgt_[2], wgt_[3]);
    r.y = blend2(pf[0].y, pf[1].y, pf[2].y, pf[3].y, wgt_[0], wgt_[1], wgt_[2], wgt_[3]);
    r.z = blend2(pf[0].z, pf[1].z, pf[2].z, pf[3].z, wgt_[0], wgt_[1], wgt_[2], wgt_[3]);
    r.w = blend2(pf[0].w, pf[1].w, pf[2].w, pf[3].w, wgt_[0], wgt_[1], wgt_[2], wgt_[3]);
    aw = r;
  };

  // prologue: blend(tile0) into aw, gather(tile1) in flight
  prep(0);
  issueA(0);
  blendA();
  issueA(1);

  char* AB = (char*)Alds;
  char* BB = (char*)Blds;

  for (int it = 0; it < NIT; ++it) {
    // ---- phase A: stage A from registers; B via global_load_lds ----
    *(uint4*)(AB + AldsOff) = aw;
    {
      const unsigned short* wTit = wT + it * 64;
#pragma unroll
      for (int t = 0; t < 4; ++t)
        glds16((const unsigned short*)((const char*)wTit + BsrcC[t]),
               (unsigned short*)(BB + BldsC[t]));
    }
    asm volatile("s_waitcnt vmcnt(0) lgkmcnt(0)" ::: "memory");
    __builtin_amdgcn_s_barrier();
    asm volatile("" ::: "memory");

    // ---- phase B: blend next A tile, issue gather(it+2), MFMA current ----
    int nx = it + 1;
    if (nx < NIT) {
      blendA();                        // consumes pf (data for tile nx)
      int nn = it + 2;
      if (nn < NIT) {
        if ((nn & 3) == 0) prep(nn >> 2);
        issueA(nn & 3);                // flies across next phase A's vmcnt
      }
    }

#pragma unroll
    for (int ksi = 0; ksi < 2; ++ksi) {
      int rc = ksi ? rc1 : rc0;
      short8 af[2];
#pragma unroll
      for (int i = 0; i < 2; ++i)
        af[i] = *(const short8*)(AB + (wm + i * 16 + l15) * 128 + rc);
#pragma unroll
      for (int j = 0; j < 4; ++j) {
        short8 bf = *(const short8*)(BB + (wn + j * 16 + l15) * 128 + rc);
#pragma unroll
        for (int i = 0; i < 2; ++i)
          acc[i][j] = __builtin_amdgcn_mfma_f32_16x16x32_bf16(af[i], bf, acc[i][j], 0, 0, 0);
      }
    }
    asm volatile("s_waitcnt lgkmcnt(0)" ::: "memory");
    __builtin_amdgcn_s_barrier();
    asm volatile("" ::: "memory");
  }

  // ---- epilogue: out[n][co][h][w], float4 along w ----
  float* outp = out + (size_t)n * COUT * HW + (size_t)h * WW + mh * 64;
#pragma unroll
  for (int i = 0; i < 2; ++i) {
    int w0 = wm + i * 16 + l4 * 4;
#pragma unroll
    for (int j = 0; j < 4; ++j) {
      int co = wn + j * 16 + l15;
      *(f32x4*)(outp + (size_t)co * HW + w0) = acc[i][j];
    }
  }
}

extern "C" void kernel_launch(void* const* d_in, const int* in_sizes, int n_in,
                              void* d_out, int out_size, void* d_ws, size_t ws_size,
                              hipStream_t stream) {
  const float* x = (const float*)d_in[0];
  const float* obb = (const float*)d_in[1];
  const float* wgt = (const float*)d_in[2];
  const int* stridep = (const int*)d_in[3];
  float* out = (float*)d_out;

  unsigned short* xt = (unsigned short*)d_ws;          // 2*128*128*256 bf16 = 16.8 MB
  unsigned short* wT = xt + (size_t)2 * HH * WW * CIN; // 256*2304 bf16 = 1.2 MB

  prep_inputs<<<dim3(1024 + 2304), 256, 0, stream>>>(x, wgt, xt, wT);
  fused_deform_gemm<<<dim3(512), 512, 0, stream>>>(obb, xt, wT, out, stridep);
}